// Round 23
// baseline (121.499 us; speedup 1.0000x reference)
//
#include <hip/hip_runtime.h>

#define NG 32
#define NODES 4096
#define NTOT (NG * NODES)      // 131072
#define DIN 128
#define HID 16
#define ODIM 39
#define NEDGE (NTOT * 32)      // 4194304
#define EPG (NEDGE / NG)       // 131072 edges per graph
#define CH  32                 // chunks per graph
#define CHE 4096               // edges per chunk

typedef unsigned int uint;
typedef unsigned short ushort;

// bucket = (graph, 16-node segment): 8192 buckets, payload u16
#define NB   8192
#define BCAP 768               // mean 512, +11 sigma
#define SCAP 896               // BCAP + 16*8 slack for 8-aligned per-dst slots

// k4 geometry
#define K4B  1024
#define PODS 40

// ws layout (float offsets unless noted)
#define WS_XL     0            // float[2097152]
#define WS_XR     2097152      // float[2097152]
#define WS_AGG    4194304      // float[2097152]  (holds fused h in fast path)
#define WS_CNT    6291456      // float[131072]   (fallback only)
#define WS_GCOUNT 6422528      // uint[8192]
#define PEDGE_BYTE_OFF  ((size_t)(6422528 + 8192) * 4)              // 25,722,880
#define HIST2_BYTE_OFF  (PEDGE_BYTE_OFF + (size_t)NB * BCAP * 2)    // 38,305,792 (1MB)
#define SEED2_BYTE_OFF  (HIST2_BYTE_OFF + (size_t)NG * CH * 256 * 4)// 39,354,368 (1MB)
#define PEDGE0_BYTE_OFF (SEED2_BYTE_OFF + (size_t)NG * CH * 256 * 4)// 40,402,944
#define WS_NEED_FAST    (PEDGE0_BYTE_OFF + (size_t)NEDGE * 4)       // ~57.2 MB
// partial (float[K4B*NG*PODS] = 5.24 MB) overlays pedge after kS_reg.

// ---------------------------------------------------------------------------
// k1 (R18-proven LDS version): xl = x @ Wl^T, xr = x @ Wr^T, one pass over x.
// ---------------------------------------------------------------------------
__global__ __launch_bounds__(256) void k1_lin(const float* __restrict__ x,
                                              const float* __restrict__ Wl,
                                              const float* __restrict__ Wr,
                                              float* __restrict__ xl,
                                              float* __restrict__ xr) {
    __shared__ float xs[64 * 132];
    __shared__ float wls[16 * 132];
    __shared__ float wrs[16 * 132];
    const int t = threadIdx.x;

    #pragma unroll
    for (int i = 0; i < 2; ++i) {
        int f = i * 256 + t;
        int o = f >> 5, k4 = f & 31;
        float4 a = reinterpret_cast<const float4*>(Wl)[f];
        float4 b = reinterpret_cast<const float4*>(Wr)[f];
        *reinterpret_cast<float4*>(&wls[o * 132 + 4 * k4]) = a;
        *reinterpret_cast<float4*>(&wrs[o * 132 + 4 * k4]) = b;
    }

    const long base = (long)blockIdx.x * 64;
    const float4* xg = reinterpret_cast<const float4*>(x) + base * 32;
    #pragma unroll
    for (int i = 0; i < 8; ++i) {
        int f = i * 256 + t;
        int n = f >> 5, k4 = f & 31;
        *reinterpret_cast<float4*>(&xs[n * 132 + 4 * k4]) = xg[f];
    }
    __syncthreads();

    const int o = t & 15, ngrp = t >> 4;
    float accl[4] = {0.f, 0.f, 0.f, 0.f};
    float accr[4] = {0.f, 0.f, 0.f, 0.f};
    for (int k4 = 0; k4 < 32; ++k4) {
        float4 w0 = *reinterpret_cast<const float4*>(&wls[o * 132 + 4 * k4]);
        float4 w1 = *reinterpret_cast<const float4*>(&wrs[o * 132 + 4 * k4]);
        #pragma unroll
        for (int j = 0; j < 4; ++j) {
            float4 xv = *reinterpret_cast<const float4*>(&xs[(ngrp + 16 * j) * 132 + 4 * k4]);
            accl[j] += xv.x * w0.x + xv.y * w0.y + xv.z * w0.z + xv.w * w0.w;
            accr[j] += xv.x * w1.x + xv.y * w1.y + xv.z * w1.z + xv.w * w1.w;
        }
    }
    #pragma unroll
    for (int j = 0; j < 4; ++j) {
        long n = base + ngrp + 16 * j;
        xl[n * HID + o] = accl[j];
        xr[n * HID + o] = accr[j];
    }
}

// ---------------------------------------------------------------------------
// kT: repack edge_index into per-graph contiguous u32 (sl | dl<<16).
// ---------------------------------------------------------------------------
__global__ __launch_bounds__(1024) void kT_pack(const int* __restrict__ ei,
                                                uint* __restrict__ pedge0) {
    __shared__ uint st[32 * 129];
    const int b = blockIdx.x;       // 1024 blocks x 4096 edges
    const int t = threadIdx.x;
    const int e0 = b * 4096;
    #pragma unroll
    for (int j = 0; j < 4; ++j) {
        int e = e0 + j * 1024 + t;
        uint s = (uint)ei[e] & 4095u;
        uint d = (uint)ei[NEDGE + e] & 4095u;
        int g = e & 31;
        int i = (e >> 5) & 127;
        st[g * 129 + i] = s | (d << 16);
    }
    __syncthreads();
    #pragma unroll
    for (int j = 0; j < 4; ++j) {
        int o = j * 1024 + t;
        int g = o >> 7, i = o & 127;
        pedge0[(size_t)g * EPG + b * 128 + i] = st[g * 129 + i];
    }
}

// ---------------------------------------------------------------------------
// kH2: block = (graph, chunk). Histogram chunk's 4096 edges over 256 segments.
// ---------------------------------------------------------------------------
__global__ __launch_bounds__(256) void kH2(const uint* __restrict__ pedge0,
                                           uint* __restrict__ hist2) {
    __shared__ uint lh[256];
    const int bid = blockIdx.x;         // 0..1023
    const int g = bid >> 5, c = bid & 31;
    const int t = threadIdx.x;
    lh[t] = 0u;
    __syncthreads();
    const uint4* pe = reinterpret_cast<const uint4*>(pedge0 + (size_t)g * EPG + c * CHE);
    #pragma unroll
    for (int j = 0; j < 4; ++j) {
        uint4 p = pe[j * 256 + t];
        atomicAdd(&lh[(p.x >> 20) & 255], 1u);
        atomicAdd(&lh[(p.y >> 20) & 255], 1u);
        atomicAdd(&lh[(p.z >> 20) & 255], 1u);
        atomicAdd(&lh[(p.w >> 20) & 255], 1u);
    }
    __syncthreads();
    hist2[(size_t)bid * 256 + t] = lh[t];
}

// ---------------------------------------------------------------------------
// kScan2: block per graph; thread t owns bucket (g,t). Serial scan over the
//         32 chunk-counts; seeds -> seed2 (hist2 keeps raw counts for kB3).
// ---------------------------------------------------------------------------
__global__ __launch_bounds__(256) void kScan2(const uint* __restrict__ hist2,
                                              uint* __restrict__ seed2,
                                              uint* __restrict__ gcount) {
    const int g = blockIdx.x;           // 0..31
    const int t = threadIdx.x;          // segment
    uint run = 0u;
    for (int c = 0; c < CH; ++c) {
        size_t idx = (size_t)(g * CH + c) * 256 + t;
        uint v = hist2[idx];
        seed2[idx] = run;               // exclusive prefix across chunks
        run += v;
    }
    gcount[g * 256 + t] = run;
}

// ---------------------------------------------------------------------------
// kB3: counting-sort chunk by segment in LDS. Counts loaded from hist2
//      (no recount); shfl wave-scan; dense target-indexed write-out.
// ---------------------------------------------------------------------------
__global__ __launch_bounds__(256) void kB3(const uint* __restrict__ pedge0,
                                           const uint* __restrict__ hist2,
                                           const uint* __restrict__ seed2,
                                           ushort* __restrict__ pedge) {
    __shared__ ushort sorted[CHE];      // 8 KB
    __shared__ uint tgt[CHE];           // 16 KB
    __shared__ uint lstart[256];
    __shared__ uint gseed[256];
    __shared__ uint cur[256];
    __shared__ uint wsum[4];
    const int bid = blockIdx.x;         // 0..1023
    const int g = bid >> 5, c = bid & 31;
    const int t = threadIdx.x;
    const int lane = t & 63, w = t >> 6;

    // load this chunk's per-segment counts + global seeds (coalesced 1KB each)
    const uint v = hist2[(size_t)bid * 256 + t];
    gseed[t] = seed2[(size_t)bid * 256 + t];

    const uint4* pe = reinterpret_cast<const uint4*>(pedge0 + (size_t)g * EPG + c * CHE);
    uint4 loc[4];
    #pragma unroll
    for (int j = 0; j < 4; ++j) loc[j] = pe[j * 256 + t];

    // exclusive scan of counts via shfl wave-scan + 4-wave combine
    {
        uint inc = v;
        #pragma unroll
        for (int off = 1; off < 64; off <<= 1) {
            uint u = __shfl_up(inc, off, 64);
            if (lane >= off) inc += u;
        }
        if (lane == 63) wsum[w] = inc;
        __syncthreads();
        uint base = 0u;
        #pragma unroll
        for (int ww = 0; ww < 4; ++ww)
            if (ww < w) base += wsum[ww];
        uint ls = base + inc - v;
        lstart[t] = ls;
        cur[t] = ls;
    }
    __syncthreads();

    // place: absolute chunk position via LDS atomic; record dense target
    #pragma unroll
    for (int j = 0; j < 4; ++j) {
        uint p;
        #pragma unroll
        for (int q = 0; q < 4; ++q) {
            p = (q == 0) ? loc[j].x : (q == 1) ? loc[j].y : (q == 2) ? loc[j].z : loc[j].w;
            uint s = (p >> 20) & 255u;
            uint idx = atomicAdd(&cur[s], 1u);
            sorted[idx] = (ushort)((p & 4095u) | (((p >> 16) & 15u) << 12));
            tgt[idx] = (s << 10) | (gseed[s] + (idx - lstart[s]));
        }
    }
    __syncthreads();

    // dense write-out: consecutive i in a run -> consecutive global addresses
    #pragma unroll
    for (int it = 0; it < CHE / 256; ++it) {
        int i = it * 256 + t;
        uint tg = tgt[i];
        uint s = tg >> 10, pos = tg & 1023u;
        if (pos < BCAP)
            pedge[(size_t)(g * 256 + s) * BCAP + pos] = sorted[i];
    }
}

// ---------------------------------------------------------------------------
// kS_reg v9: block per bucket. Rank-keeping count pass; wave-0 scan with
// 8-ALIGNED per-dst slot offsets; plain-store place; gather with BATCHED
// indices: one ds_read_b128 = 8 indices -> 8 independent 16B global loads
// in flight per thread (8x MLP vs scalar chain). shfl_xor combine + fused
// epilogue h = relu(sum/max(cnt,1)+bl+xr).
// ---------------------------------------------------------------------------
__global__ __launch_bounds__(256) void kS_reg(const uint* __restrict__ gcount,
                                              const ushort* __restrict__ pedge,
                                              const float* __restrict__ xl,
                                              const float* __restrict__ xr,
                                              const float* __restrict__ bl,
                                              float* __restrict__ hout) {
    __shared__ ushort sorted[SCAP];
    __shared__ uint c16[16];
    __shared__ uint off16[16];
    const int b = blockIdx.x;            // 0..8191
    const int g = b >> 8, seg = b & 255;
    const int t = threadIdx.x;

    if (t < 16) c16[t] = 0u;
    int n = (int)gcount[b];
    if (n > BCAP) n = BCAP;
    const size_t bo = (size_t)b * BCAP;
    __syncthreads();

    // count pass: keep rank (atomic return) in registers
    uint rv[3], rk[3];
    #pragma unroll
    for (int j = 0; j < 3; ++j) {
        int i = t + j * 256;
        rv[j] = 0xFFFFFFFFu;
        if (i < n) {
            ushort p = pedge[bo + i];
            rv[j] = p;
            rk[j] = atomicAdd(&c16[p >> 12], 1u);
        }
    }
    __syncthreads();

    // wave-0 shfl exclusive scan of ROUNDED-UP counts (8-aligned slots)
    if (t < 64) {
        uint v = (t < 16) ? ((c16[t] + 7u) & ~7u) : 0u;
        uint inc = v;
        #pragma unroll
        for (int off = 1; off < 16; off <<= 1) {
            uint u = __shfl_up(inc, off, 64);
            if (t >= off) inc += u;
        }
        if (t < 16) off16[t] = inc - v;
    }
    __syncthreads();

    // place from registers: plain store at off16[d] + rank
    #pragma unroll
    for (int j = 0; j < 3; ++j) {
        uint p = rv[j];
        if (p != 0xFFFFFFFFu)
            sorted[off16[p >> 12] + rk[j]] = (ushort)(p & 4095u);
    }
    __syncthreads();

    // batched quad gather: thread = (dst=t>>4, qi=(t>>2)&3, ch4=t&3).
    // quad qi covers i in [qi*8, qi*8+8) stride 32; 8 contiguous indices
    // per step -> one uint4 LDS read + 8 independent global float4 loads.
    const int dlo = t >> 4;
    const int qi  = (t >> 2) & 3;
    const int ch4 = t & 3;
    const uint start = off16[dlo];       // 8-aligned
    const uint len = c16[dlo];
    const float4* xrow4 = reinterpret_cast<const float4*>(xl + (((size_t)g << 12) * HID)) + ch4;
    float4 acc = {0.f, 0.f, 0.f, 0.f};
    for (uint bi = (uint)qi * 8u; bi < len; bi += 32u) {
        uint c8 = len - bi;
        if (c8 >= 8u) {
            uint4 ix = *reinterpret_cast<const uint4*>(&sorted[start + bi]); // 16B aligned
            int e0 = ix.x & 0xFFFF, e1 = ix.x >> 16;
            int e2 = ix.y & 0xFFFF, e3 = ix.y >> 16;
            int e4 = ix.z & 0xFFFF, e5 = ix.z >> 16;
            int e6 = ix.w & 0xFFFF, e7 = ix.w >> 16;
            float4 v0 = xrow4[e0 * 4];
            float4 v1 = xrow4[e1 * 4];
            float4 v2 = xrow4[e2 * 4];
            float4 v3 = xrow4[e3 * 4];
            float4 v4 = xrow4[e4 * 4];
            float4 v5 = xrow4[e5 * 4];
            float4 v6 = xrow4[e6 * 4];
            float4 v7 = xrow4[e7 * 4];
            acc.x += ((v0.x + v1.x) + (v2.x + v3.x)) + ((v4.x + v5.x) + (v6.x + v7.x));
            acc.y += ((v0.y + v1.y) + (v2.y + v3.y)) + ((v4.y + v5.y) + (v6.y + v7.y));
            acc.z += ((v0.z + v1.z) + (v2.z + v3.z)) + ((v4.z + v5.z) + (v6.z + v7.z));
            acc.w += ((v0.w + v1.w) + (v2.w + v3.w)) + ((v4.w + v5.w) + (v6.w + v7.w));
        } else {
            for (uint i = bi; i < len; ++i) {
                int sl = sorted[start + i];
                float4 v = xrow4[sl * 4];
                acc.x += v.x; acc.y += v.y; acc.z += v.z; acc.w += v.w;
            }
        }
    }

    // cross-qi reduce within the wave (bits 2,3 of t = qi)
    #pragma unroll
    for (int m = 4; m <= 8; m <<= 1) {
        acc.x += __shfl_xor(acc.x, m, 64);
        acc.y += __shfl_xor(acc.y, m, 64);
        acc.z += __shfl_xor(acc.z, m, 64);
        acc.w += __shfl_xor(acc.w, m, 64);
    }

    // qi==0 lanes: fused epilogue + coalesced float4 store
    if (qi == 0) {
        const float cn = fmaxf((float)len, 1.0f);
        const float4 b4 = reinterpret_cast<const float4*>(bl)[ch4];
        const size_t base = (((size_t)g << 12) + (seg << 4) + dlo) * HID + ch4 * 4;
        const float4 xv = *reinterpret_cast<const float4*>(&xr[base]);
        float4 hv;
        hv.x = fmaxf(acc.x / cn + b4.x + xv.x, 0.f);
        hv.y = fmaxf(acc.y / cn + b4.y + xv.y, 0.f);
        hv.z = fmaxf(acc.z / cn + b4.z + xv.z, 0.f);
        hv.w = fmaxf(acc.w / cn + b4.w + xv.w, 0.f);
        *reinterpret_cast<float4*>(&hout[base]) = hv;
    }
}

// ---------------------------------------------------------------------------
// k4b v2: skinny GEMM over kk-tile 64, reading PRE-FUSED h (single stream).
// ---------------------------------------------------------------------------
__global__ __launch_bounds__(256, 4) void k4b_out(const float* __restrict__ hfeat,
                                                  const float* __restrict__ Wout,
                                                  float* __restrict__ partial) {
    __shared__ float hs[32 * 64];      // [g][kk]
    __shared__ float wt[39 * 68];      // [od][kk] pad 64->68
    const int t = threadIdx.x;
    const int kb = blockIdx.x;         // 0..1023
    const int kbase = kb * 64;

    #pragma unroll
    for (int r = 0; r < 2; ++r) {
        int idx = r * 256 + t;         // 0..511 float4s
        int g = idx >> 4, kk4 = idx & 15;
        float4 hv = *reinterpret_cast<const float4*>(
            &hfeat[(size_t)g * (NODES * HID) + kbase + kk4 * 4]);
        *reinterpret_cast<float4*>(&hs[g * 64 + kk4 * 4]) = hv;
    }
    for (int idx = t; idx < ODIM * 64; idx += 256) {
        int od = idx >> 6, kk = idx & 63;
        wt[od * 68 + kk] = Wout[(long)od * (NODES * HID) + kbase + kk];
    }
    __syncthreads();

    const int tod = t & 31, tg = t >> 5;
    const int od0 = tod;
    const bool has1 = (tod + 32) < ODIM;
    const int od1 = has1 ? tod + 32 : tod;
    float acc0[4] = {0.f, 0.f, 0.f, 0.f};
    float acc1[4] = {0.f, 0.f, 0.f, 0.f};
    #pragma unroll 4
    for (int k4 = 0; k4 < 16; ++k4) {
        float4 w0 = *reinterpret_cast<const float4*>(&wt[od0 * 68 + 4 * k4]);
        float4 w1 = *reinterpret_cast<const float4*>(&wt[od1 * 68 + 4 * k4]);
        #pragma unroll
        for (int j = 0; j < 4; ++j) {
            float4 h4 = *reinterpret_cast<const float4*>(&hs[(tg * 4 + j) * 64 + 4 * k4]);
            acc0[j] += h4.x * w0.x + h4.y * w0.y + h4.z * w0.z + h4.w * w0.w;
            acc1[j] += h4.x * w1.x + h4.y * w1.y + h4.z * w1.z + h4.w * w1.w;
        }
    }
    float* pb = partial + (size_t)kb * (NG * PODS);
    #pragma unroll
    for (int j = 0; j < 4; ++j) {
        int g = tg * 4 + j;
        pb[g * PODS + od0] = acc0[j];
        if (has1) pb[g * PODS + od1] = acc1[j];
    }
}

// ---------------------------------------------------------------------------
// kR2: parallel tree reduce. Block per (g, od).
// ---------------------------------------------------------------------------
__global__ __launch_bounds__(256) void kR2_reduce(const float* __restrict__ partial,
                                                  const float* __restrict__ bout,
                                                  float* __restrict__ out) {
    const int b = blockIdx.x;            // 0..1279
    const int g = b / PODS, od = b - g * PODS;
    if (od >= ODIM) return;
    const int t = threadIdx.x;
    const float* p = partial + g * PODS + od;
    float acc = 0.f;
    #pragma unroll
    for (int i = 0; i < K4B / 256; ++i)
        acc += p[(size_t)(i * 256 + t) * (NG * PODS)];
    #pragma unroll
    for (int off = 32; off > 0; off >>= 1)
        acc += __shfl_down(acc, off, 64);
    __shared__ float w4[4];
    if ((t & 63) == 0) w4[t >> 6] = acc;
    __syncthreads();
    if (t == 0)
        out[g * ODIM + od] = w4[0] + w4[1] + w4[2] + w4[3] + bout[od];
}

// ---------------------------------------------------------------------------
// fallback (small ws): global-atomic scatter + atomic k4
// ---------------------------------------------------------------------------
__global__ __launch_bounds__(256) void k2_edges(const int* __restrict__ ei,
                                                const float* __restrict__ xl,
                                                float* __restrict__ agg,
                                                float* __restrict__ cnt) {
    const long tid = (long)blockIdx.x * 256 + threadIdx.x;
    const int e = (int)(tid >> 4);
    const int c = (int)(tid & 15);
    const int s = ei[e];
    const int d = ei[NEDGE + e];
    const float v = xl[(long)s * HID + c];
    atomicAdd(&agg[(long)d * HID + c], v);
    if (c == 0) atomicAdd(&cnt[d], 1.0f);
}

__global__ __launch_bounds__(256) void k3_init_out(const float* __restrict__ bout,
                                                   float* __restrict__ out) {
    int i = blockIdx.x * 256 + threadIdx.x;
    if (i < NG * ODIM) out[i] = bout[i % ODIM];
}

__global__ __launch_bounds__(256) void k4_out(const float* __restrict__ agg,
                                              const float* __restrict__ cnt,
                                              const float* __restrict__ xr,
                                              const float* __restrict__ bl,
                                              const float* __restrict__ Wout,
                                              float* __restrict__ out) {
    __shared__ float hs[32 * 128];
    __shared__ float wt[39 * 132];
    const int t = threadIdx.x;
    const int kbase = blockIdx.x * 128;

    #pragma unroll
    for (int r = 0; r < 16; ++r) {
        int idx = r * 256 + t;
        int g = idx >> 7, kk = idx & 127;
        long flat = (long)g * (NODES * HID) + kbase + kk;
        float a = agg[flat];
        float xv = xr[flat];
        float cn = cnt[(g << 12) + ((kbase + kk) >> 4)];
        float h = a / fmaxf(cn, 1.0f) + bl[kk & 15] + xv;
        hs[g * 128 + kk] = fmaxf(h, 0.0f);
    }
    for (int idx = t; idx < ODIM * 128; idx += 256) {
        int od = idx >> 7, kk = idx & 127;
        wt[od * 132 + kk] = Wout[(long)od * (NODES * HID) + kbase + kk];
    }
    __syncthreads();

    const int tod = t & 31, tg = t >> 5;
    const int od0 = tod;
    const bool has1 = (tod + 32) < ODIM;
    const int od1 = has1 ? tod + 32 : tod;
    float acc0[4] = {0.f, 0.f, 0.f, 0.f};
    float acc1[4] = {0.f, 0.f, 0.f, 0.f};
    for (int k4 = 0; k4 < 32; ++k4) {
        float4 w0 = *reinterpret_cast<const float4*>(&wt[od0 * 132 + 4 * k4]);
        float4 w1 = *reinterpret_cast<const float4*>(&wt[od1 * 132 + 4 * k4]);
        #pragma unroll
        for (int j = 0; j < 4; ++j) {
            float4 h4 = *reinterpret_cast<const float4*>(&hs[(tg * 4 + j) * 128 + 4 * k4]);
            acc0[j] += h4.x * w0.x + h4.y * w0.y + h4.z * w0.z + h4.w * w0.w;
            acc1[j] += h4.x * w1.x + h4.y * w1.y + h4.z * w1.z + h4.w * w1.w;
        }
    }
    #pragma unroll
    for (int j = 0; j < 4; ++j) {
        int g = tg * 4 + j;
        atomicAdd(&out[g * ODIM + od0], acc0[j]);
        if (has1) atomicAdd(&out[g * ODIM + od1], acc1[j]);
    }
}

// ---------------------------------------------------------------------------
extern "C" void kernel_launch(void* const* d_in, const int* in_sizes, int n_in,
                              void* d_out, int out_size, void* d_ws, size_t ws_size,
                              hipStream_t stream) {
    const float* x    = (const float*)d_in[0];
    const int*   ei   = (const int*)d_in[1];
    const float* Wl   = (const float*)d_in[2];
    const float* bl   = (const float*)d_in[3];
    const float* Wr   = (const float*)d_in[4];
    const float* Wout = (const float*)d_in[5];
    const float* bout = (const float*)d_in[6];
    float* out = (float*)d_out;
    float* ws  = (float*)d_ws;

    float* xl  = ws + WS_XL;
    float* xr  = ws + WS_XR;
    float* agg = ws + WS_AGG;    // fast path: holds fused h
    float* cnt = ws + WS_CNT;    // fallback only

    if (ws_size >= WS_NEED_FAST) {
        uint*   gcount  = (uint*)(ws + WS_GCOUNT);
        ushort* pedge   = (ushort*)((char*)d_ws + PEDGE_BYTE_OFF);
        uint*   hist2   = (uint*)((char*)d_ws + HIST2_BYTE_OFF);
        uint*   seed2   = (uint*)((char*)d_ws + SEED2_BYTE_OFF);
        uint*   pedge0  = (uint*)((char*)d_ws + PEDGE0_BYTE_OFF);
        float*  partial = (float*)((char*)d_ws + PEDGE_BYTE_OFF); // after kS

        k1_lin<<<NTOT / 64, 256, 0, stream>>>(x, Wl, Wr, xl, xr);
        kT_pack<<<NEDGE / 4096, 1024, 0, stream>>>(ei, pedge0);
        kH2<<<NG * CH, 256, 0, stream>>>(pedge0, hist2);
        kScan2<<<NG, 256, 0, stream>>>(hist2, seed2, gcount);
        kB3<<<NG * CH, 256, 0, stream>>>(pedge0, hist2, seed2, pedge);
        kS_reg<<<NB, 256, 0, stream>>>(gcount, pedge, xl, xr, bl, agg);
        k4b_out<<<K4B, 256, 0, stream>>>(agg, Wout, partial);
        kR2_reduce<<<NG * PODS, 256, 0, stream>>>(partial, bout, out);
    } else {
        hipMemsetAsync(agg, 0, (size_t)(NTOT * HID + NTOT) * sizeof(float), stream);
        k1_lin<<<NTOT / 64, 256, 0, stream>>>(x, Wl, Wr, xl, xr);
        k2_edges<<<(long)NEDGE * 16 / 256, 256, 0, stream>>>(ei, xl, agg, cnt);
        k3_init_out<<<(NG * ODIM + 255) / 256, 256, 0, stream>>>(bout, out);
        k4_out<<<(NODES * HID) / 128, 256, 0, stream>>>(agg, cnt, xr, bl, Wout, out);
    }
}

// Round 24
// 114.609 us; speedup vs baseline: 1.0601x; 1.0601x over previous
//
#include <hip/hip_runtime.h>

#define NG 32
#define NODES 4096
#define NTOT (NG * NODES)      // 131072
#define DIN 128
#define HID 16
#define ODIM 39
#define NEDGE (NTOT * 32)      // 4194304
#define EPG (NEDGE / NG)       // 131072 edges per graph
#define CH  32                 // chunks per graph
#define CHE 4096               // edges per chunk

typedef unsigned int uint;
typedef unsigned short ushort;

// bucket = (graph, 16-node segment): 8192 buckets, payload u16
#define NB   8192
#define BCAP 768               // mean 512, +11 sigma

// k4 geometry
#define K4B  1024
#define PODS 40

// ws layout (float offsets unless noted)
#define WS_XL     0            // float[2097152]
#define WS_XR     2097152      // float[2097152]
#define WS_AGG    4194304      // float[2097152]  (holds fused h in fast path)
#define WS_CNT    6291456      // float[131072]   (fallback only)
#define WS_GCOUNT 6422528      // uint[8192]
#define PEDGE_BYTE_OFF  ((size_t)(6422528 + 8192) * 4)              // 25,722,880
#define HIST2_BYTE_OFF  (PEDGE_BYTE_OFF + (size_t)NB * BCAP * 2)    // 38,305,792 (1MB)
#define SEED2_BYTE_OFF  (HIST2_BYTE_OFF + (size_t)NG * CH * 256 * 4)// 39,354,368 (1MB)
#define PEDGE0_BYTE_OFF (SEED2_BYTE_OFF + (size_t)NG * CH * 256 * 4)// 40,402,944
#define WS_NEED_FAST    (PEDGE0_BYTE_OFF + (size_t)NEDGE * 4)       // ~57.2 MB
// partial (float[K4B*NG*PODS] = 5.24 MB) overlays pedge after kS_reg.

// ---------------------------------------------------------------------------
// k1 (R18-proven LDS version): xl = x @ Wl^T, xr = x @ Wr^T, one pass over x.
// ---------------------------------------------------------------------------
__global__ __launch_bounds__(256) void k1_lin(const float* __restrict__ x,
                                              const float* __restrict__ Wl,
                                              const float* __restrict__ Wr,
                                              float* __restrict__ xl,
                                              float* __restrict__ xr) {
    __shared__ float xs[64 * 132];
    __shared__ float wls[16 * 132];
    __shared__ float wrs[16 * 132];
    const int t = threadIdx.x;

    #pragma unroll
    for (int i = 0; i < 2; ++i) {
        int f = i * 256 + t;
        int o = f >> 5, k4 = f & 31;
        float4 a = reinterpret_cast<const float4*>(Wl)[f];
        float4 b = reinterpret_cast<const float4*>(Wr)[f];
        *reinterpret_cast<float4*>(&wls[o * 132 + 4 * k4]) = a;
        *reinterpret_cast<float4*>(&wrs[o * 132 + 4 * k4]) = b;
    }

    const long base = (long)blockIdx.x * 64;
    const float4* xg = reinterpret_cast<const float4*>(x) + base * 32;
    #pragma unroll
    for (int i = 0; i < 8; ++i) {
        int f = i * 256 + t;
        int n = f >> 5, k4 = f & 31;
        *reinterpret_cast<float4*>(&xs[n * 132 + 4 * k4]) = xg[f];
    }
    __syncthreads();

    const int o = t & 15, ngrp = t >> 4;
    float accl[4] = {0.f, 0.f, 0.f, 0.f};
    float accr[4] = {0.f, 0.f, 0.f, 0.f};
    for (int k4 = 0; k4 < 32; ++k4) {
        float4 w0 = *reinterpret_cast<const float4*>(&wls[o * 132 + 4 * k4]);
        float4 w1 = *reinterpret_cast<const float4*>(&wrs[o * 132 + 4 * k4]);
        #pragma unroll
        for (int j = 0; j < 4; ++j) {
            float4 xv = *reinterpret_cast<const float4*>(&xs[(ngrp + 16 * j) * 132 + 4 * k4]);
            accl[j] += xv.x * w0.x + xv.y * w0.y + xv.z * w0.z + xv.w * w0.w;
            accr[j] += xv.x * w1.x + xv.y * w1.y + xv.z * w1.z + xv.w * w1.w;
        }
    }
    #pragma unroll
    for (int j = 0; j < 4; ++j) {
        long n = base + ngrp + 16 * j;
        xl[n * HID + o] = accl[j];
        xr[n * HID + o] = accr[j];
    }
}

// ---------------------------------------------------------------------------
// kT: repack edge_index into per-graph contiguous u32 (sl | dl<<16).
// ---------------------------------------------------------------------------
__global__ __launch_bounds__(1024) void kT_pack(const int* __restrict__ ei,
                                                uint* __restrict__ pedge0) {
    __shared__ uint st[32 * 129];
    const int b = blockIdx.x;       // 1024 blocks x 4096 edges
    const int t = threadIdx.x;
    const int e0 = b * 4096;
    #pragma unroll
    for (int j = 0; j < 4; ++j) {
        int e = e0 + j * 1024 + t;
        uint s = (uint)ei[e] & 4095u;
        uint d = (uint)ei[NEDGE + e] & 4095u;
        int g = e & 31;
        int i = (e >> 5) & 127;
        st[g * 129 + i] = s | (d << 16);
    }
    __syncthreads();
    #pragma unroll
    for (int j = 0; j < 4; ++j) {
        int o = j * 1024 + t;
        int g = o >> 7, i = o & 127;
        pedge0[(size_t)g * EPG + b * 128 + i] = st[g * 129 + i];
    }
}

// ---------------------------------------------------------------------------
// kH2: block = (graph, chunk). Histogram chunk's 4096 edges over 256 segments.
// ---------------------------------------------------------------------------
__global__ __launch_bounds__(256) void kH2(const uint* __restrict__ pedge0,
                                           uint* __restrict__ hist2) {
    __shared__ uint lh[256];
    const int bid = blockIdx.x;         // 0..1023
    const int g = bid >> 5, c = bid & 31;
    const int t = threadIdx.x;
    lh[t] = 0u;
    __syncthreads();
    const uint4* pe = reinterpret_cast<const uint4*>(pedge0 + (size_t)g * EPG + c * CHE);
    #pragma unroll
    for (int j = 0; j < 4; ++j) {
        uint4 p = pe[j * 256 + t];
        atomicAdd(&lh[(p.x >> 20) & 255], 1u);
        atomicAdd(&lh[(p.y >> 20) & 255], 1u);
        atomicAdd(&lh[(p.z >> 20) & 255], 1u);
        atomicAdd(&lh[(p.w >> 20) & 255], 1u);
    }
    __syncthreads();
    hist2[(size_t)bid * 256 + t] = lh[t];
}

// ---------------------------------------------------------------------------
// kScan2: block per graph; thread t owns bucket (g,t). Serial scan over the
//         32 chunk-counts; seeds -> seed2 (hist2 keeps raw counts for kB3).
// ---------------------------------------------------------------------------
__global__ __launch_bounds__(256) void kScan2(const uint* __restrict__ hist2,
                                              uint* __restrict__ seed2,
                                              uint* __restrict__ gcount) {
    const int g = blockIdx.x;           // 0..31
    const int t = threadIdx.x;          // segment
    uint run = 0u;
    for (int c = 0; c < CH; ++c) {
        size_t idx = (size_t)(g * CH + c) * 256 + t;
        uint v = hist2[idx];
        seed2[idx] = run;               // exclusive prefix across chunks
        run += v;
    }
    gcount[g * 256 + t] = run;
}

// ---------------------------------------------------------------------------
// kB3: counting-sort chunk by segment in LDS. Counts loaded from hist2
//      (no recount); shfl wave-scan; dense target-indexed write-out.
// ---------------------------------------------------------------------------
__global__ __launch_bounds__(256) void kB3(const uint* __restrict__ pedge0,
                                           const uint* __restrict__ hist2,
                                           const uint* __restrict__ seed2,
                                           ushort* __restrict__ pedge) {
    __shared__ ushort sorted[CHE];      // 8 KB
    __shared__ uint tgt[CHE];           // 16 KB
    __shared__ uint lstart[256];
    __shared__ uint gseed[256];
    __shared__ uint cur[256];
    __shared__ uint wsum[4];
    const int bid = blockIdx.x;         // 0..1023
    const int g = bid >> 5, c = bid & 31;
    const int t = threadIdx.x;
    const int lane = t & 63, w = t >> 6;

    // load this chunk's per-segment counts + global seeds (coalesced 1KB each)
    const uint v = hist2[(size_t)bid * 256 + t];
    gseed[t] = seed2[(size_t)bid * 256 + t];

    const uint4* pe = reinterpret_cast<const uint4*>(pedge0 + (size_t)g * EPG + c * CHE);
    uint4 loc[4];
    #pragma unroll
    for (int j = 0; j < 4; ++j) loc[j] = pe[j * 256 + t];

    // exclusive scan of counts via shfl wave-scan + 4-wave combine
    {
        uint inc = v;
        #pragma unroll
        for (int off = 1; off < 64; off <<= 1) {
            uint u = __shfl_up(inc, off, 64);
            if (lane >= off) inc += u;
        }
        if (lane == 63) wsum[w] = inc;
        __syncthreads();
        uint base = 0u;
        #pragma unroll
        for (int ww = 0; ww < 4; ++ww)
            if (ww < w) base += wsum[ww];
        uint ls = base + inc - v;
        lstart[t] = ls;
        cur[t] = ls;
    }
    __syncthreads();

    // place: absolute chunk position via LDS atomic; record dense target
    #pragma unroll
    for (int j = 0; j < 4; ++j) {
        uint p;
        #pragma unroll
        for (int q = 0; q < 4; ++q) {
            p = (q == 0) ? loc[j].x : (q == 1) ? loc[j].y : (q == 2) ? loc[j].z : loc[j].w;
            uint s = (p >> 20) & 255u;
            uint idx = atomicAdd(&cur[s], 1u);
            sorted[idx] = (ushort)((p & 4095u) | (((p >> 16) & 15u) << 12));
            tgt[idx] = (s << 10) | (gseed[s] + (idx - lstart[s]));
        }
    }
    __syncthreads();

    // dense write-out: consecutive i in a run -> consecutive global addresses
    #pragma unroll
    for (int it = 0; it < CHE / 256; ++it) {
        int i = it * 256 + t;
        uint tg = tgt[i];
        uint s = tg >> 10, pos = tg & 1023u;
        if (pos < BCAP)
            pedge[(size_t)(g * 256 + s) * BCAP + pos] = sorted[i];
    }
}

// ---------------------------------------------------------------------------
// kS_reg v6 (R20-proven best): bucket values in REGISTERS (no eb LDS); count
// from regs; wave-0 shfl scan; place from regs; quad gather; part[] combine;
// fused epilogue h = relu(sum/max(cnt,1)+bl+xr).
// ---------------------------------------------------------------------------
__global__ __launch_bounds__(256) void kS_reg(const uint* __restrict__ gcount,
                                              const ushort* __restrict__ pedge,
                                              const float* __restrict__ xl,
                                              const float* __restrict__ xr,
                                              const float* __restrict__ bl,
                                              float* __restrict__ hout) {
    __shared__ ushort sorted[BCAP];
    __shared__ uint c16[16];
    __shared__ uint off16[16];
    __shared__ uint cur16[16];
    __shared__ float4 part[16 * 4 * 4]; // [dst][qi][ch4], 4 KB
    const int b = blockIdx.x;            // 0..8191
    const int g = b >> 8, seg = b & 255;
    const int t = threadIdx.x;

    if (t < 16) c16[t] = 0u;
    int n = (int)gcount[b];
    if (n > BCAP) n = BCAP;
    const size_t bo = (size_t)b * BCAP;
    __syncthreads();

    // load into registers + count (one pass, no eb buffer)
    uint rv[3];
    #pragma unroll
    for (int j = 0; j < 3; ++j) {
        int i = t + j * 256;
        rv[j] = 0xFFFFFFFFu;
        if (i < n) {
            ushort p = pedge[bo + i];
            rv[j] = p;
            atomicAdd(&c16[p >> 12], 1u);
        }
    }
    __syncthreads();

    // wave-0 shfl exclusive scan of the 16 counts
    if (t < 64) {
        uint v = (t < 16) ? c16[t] : 0u;
        uint inc = v;
        #pragma unroll
        for (int off = 1; off < 16; off <<= 1) {
            uint u = __shfl_up(inc, off, 64);
            if (t >= off) inc += u;
        }
        if (t < 16) {
            off16[t] = inc - v;
            cur16[t] = inc - v;
        }
    }
    __syncthreads();

    // place from registers
    #pragma unroll
    for (int j = 0; j < 3; ++j) {
        uint p = rv[j];
        if (p != 0xFFFFFFFFu) {
            uint pos = atomicAdd(&cur16[p >> 12], 1u);
            sorted[pos] = (ushort)(p & 4095u);
        }
    }
    __syncthreads();

    // quad accumulate: thread = (dst, qi, ch4)
    const int dlo = t >> 4;
    const int qi  = (t >> 2) & 3;
    const int ch4 = t & 3;
    const uint start = off16[dlo];
    const uint len = c16[dlo];
    const float4* xrow4 = reinterpret_cast<const float4*>(xl + (((size_t)g << 12) * HID)) + ch4;
    float4 acc = {0.f, 0.f, 0.f, 0.f};
    for (uint i = qi; i < len; i += 4) {
        int sl = sorted[start + i];      // broadcast within quad
        float4 v = xrow4[sl * 4];
        acc.x += v.x; acc.y += v.y; acc.z += v.z; acc.w += v.w;
    }
    part[t] = acc;                       // part[dlo*16 + qi*4 + ch4]
    __syncthreads();

    // combine + fused epilogue: h = relu(sum/max(cnt,1) + bl + xr)
    if (t < 64) {
        int d = t >> 2, c4 = t & 3;
        float4 p0 = part[d * 16 + 0 * 4 + c4];
        float4 p1 = part[d * 16 + 1 * 4 + c4];
        float4 p2 = part[d * 16 + 2 * 4 + c4];
        float4 p3 = part[d * 16 + 3 * 4 + c4];
        float4 s;
        s.x = (p0.x + p1.x) + (p2.x + p3.x);
        s.y = (p0.y + p1.y) + (p2.y + p3.y);
        s.z = (p0.z + p1.z) + (p2.z + p3.z);
        s.w = (p0.w + p1.w) + (p2.w + p3.w);
        const float cn = fmaxf((float)c16[d], 1.0f);
        const float4 b4 = reinterpret_cast<const float4*>(bl)[c4];
        const size_t base = (((size_t)g << 12) + (seg << 4) + d) * HID + c4 * 4;
        const float4 xv = *reinterpret_cast<const float4*>(&xr[base]);
        float4 hv;
        hv.x = fmaxf(s.x / cn + b4.x + xv.x, 0.f);
        hv.y = fmaxf(s.y / cn + b4.y + xv.y, 0.f);
        hv.z = fmaxf(s.z / cn + b4.z + xv.z, 0.f);
        hv.w = fmaxf(s.w / cn + b4.w + xv.w, 0.f);
        *reinterpret_cast<float4*>(&hout[base]) = hv;
    }
}

// ---------------------------------------------------------------------------
// k4b v2: skinny GEMM over kk-tile 64, reading PRE-FUSED h (single stream).
// ---------------------------------------------------------------------------
__global__ __launch_bounds__(256, 4) void k4b_out(const float* __restrict__ hfeat,
                                                  const float* __restrict__ Wout,
                                                  float* __restrict__ partial) {
    __shared__ float hs[32 * 64];      // [g][kk]
    __shared__ float wt[39 * 68];      // [od][kk] pad 64->68
    const int t = threadIdx.x;
    const int kb = blockIdx.x;         // 0..1023
    const int kbase = kb * 64;

    #pragma unroll
    for (int r = 0; r < 2; ++r) {
        int idx = r * 256 + t;         // 0..511 float4s
        int g = idx >> 4, kk4 = idx & 15;
        float4 hv = *reinterpret_cast<const float4*>(
            &hfeat[(size_t)g * (NODES * HID) + kbase + kk4 * 4]);
        *reinterpret_cast<float4*>(&hs[g * 64 + kk4 * 4]) = hv;
    }
    for (int idx = t; idx < ODIM * 64; idx += 256) {
        int od = idx >> 6, kk = idx & 63;
        wt[od * 68 + kk] = Wout[(long)od * (NODES * HID) + kbase + kk];
    }
    __syncthreads();

    const int tod = t & 31, tg = t >> 5;
    const int od0 = tod;
    const bool has1 = (tod + 32) < ODIM;
    const int od1 = has1 ? tod + 32 : tod;
    float acc0[4] = {0.f, 0.f, 0.f, 0.f};
    float acc1[4] = {0.f, 0.f, 0.f, 0.f};
    #pragma unroll 4
    for (int k4 = 0; k4 < 16; ++k4) {
        float4 w0 = *reinterpret_cast<const float4*>(&wt[od0 * 68 + 4 * k4]);
        float4 w1 = *reinterpret_cast<const float4*>(&wt[od1 * 68 + 4 * k4]);
        #pragma unroll
        for (int j = 0; j < 4; ++j) {
            float4 h4 = *reinterpret_cast<const float4*>(&hs[(tg * 4 + j) * 64 + 4 * k4]);
            acc0[j] += h4.x * w0.x + h4.y * w0.y + h4.z * w0.z + h4.w * w0.w;
            acc1[j] += h4.x * w1.x + h4.y * w1.y + h4.z * w1.z + h4.w * w1.w;
        }
    }
    float* pb = partial + (size_t)kb * (NG * PODS);
    #pragma unroll
    for (int j = 0; j < 4; ++j) {
        int g = tg * 4 + j;
        pb[g * PODS + od0] = acc0[j];
        if (has1) pb[g * PODS + od1] = acc1[j];
    }
}

// ---------------------------------------------------------------------------
// kR2: parallel tree reduce. Block per (g, od).
// ---------------------------------------------------------------------------
__global__ __launch_bounds__(256) void kR2_reduce(const float* __restrict__ partial,
                                                  const float* __restrict__ bout,
                                                  float* __restrict__ out) {
    const int b = blockIdx.x;            // 0..1279
    const int g = b / PODS, od = b - g * PODS;
    if (od >= ODIM) return;
    const int t = threadIdx.x;
    const float* p = partial + g * PODS + od;
    float acc = 0.f;
    #pragma unroll
    for (int i = 0; i < K4B / 256; ++i)
        acc += p[(size_t)(i * 256 + t) * (NG * PODS)];
    #pragma unroll
    for (int off = 32; off > 0; off >>= 1)
        acc += __shfl_down(acc, off, 64);
    __shared__ float w4[4];
    if ((t & 63) == 0) w4[t >> 6] = acc;
    __syncthreads();
    if (t == 0)
        out[g * ODIM + od] = w4[0] + w4[1] + w4[2] + w4[3] + bout[od];
}

// ---------------------------------------------------------------------------
// fallback (small ws): global-atomic scatter + atomic k4
// ---------------------------------------------------------------------------
__global__ __launch_bounds__(256) void k2_edges(const int* __restrict__ ei,
                                                const float* __restrict__ xl,
                                                float* __restrict__ agg,
                                                float* __restrict__ cnt) {
    const long tid = (long)blockIdx.x * 256 + threadIdx.x;
    const int e = (int)(tid >> 4);
    const int c = (int)(tid & 15);
    const int s = ei[e];
    const int d = ei[NEDGE + e];
    const float v = xl[(long)s * HID + c];
    atomicAdd(&agg[(long)d * HID + c], v);
    if (c == 0) atomicAdd(&cnt[d], 1.0f);
}

__global__ __launch_bounds__(256) void k3_init_out(const float* __restrict__ bout,
                                                   float* __restrict__ out) {
    int i = blockIdx.x * 256 + threadIdx.x;
    if (i < NG * ODIM) out[i] = bout[i % ODIM];
}

__global__ __launch_bounds__(256) void k4_out(const float* __restrict__ agg,
                                              const float* __restrict__ cnt,
                                              const float* __restrict__ xr,
                                              const float* __restrict__ bl,
                                              const float* __restrict__ Wout,
                                              float* __restrict__ out) {
    __shared__ float hs[32 * 128];
    __shared__ float wt[39 * 132];
    const int t = threadIdx.x;
    const int kbase = blockIdx.x * 128;

    #pragma unroll
    for (int r = 0; r < 16; ++r) {
        int idx = r * 256 + t;
        int g = idx >> 7, kk = idx & 127;
        long flat = (long)g * (NODES * HID) + kbase + kk;
        float a = agg[flat];
        float xv = xr[flat];
        float cn = cnt[(g << 12) + ((kbase + kk) >> 4)];
        float h = a / fmaxf(cn, 1.0f) + bl[kk & 15] + xv;
        hs[g * 128 + kk] = fmaxf(h, 0.0f);
    }
    for (int idx = t; idx < ODIM * 128; idx += 256) {
        int od = idx >> 7, kk = idx & 127;
        wt[od * 132 + kk] = Wout[(long)od * (NODES * HID) + kbase + kk];
    }
    __syncthreads();

    const int tod = t & 31, tg = t >> 5;
    const int od0 = tod;
    const bool has1 = (tod + 32) < ODIM;
    const int od1 = has1 ? tod + 32 : tod;
    float acc0[4] = {0.f, 0.f, 0.f, 0.f};
    float acc1[4] = {0.f, 0.f, 0.f, 0.f};
    for (int k4 = 0; k4 < 32; ++k4) {
        float4 w0 = *reinterpret_cast<const float4*>(&wt[od0 * 132 + 4 * k4]);
        float4 w1 = *reinterpret_cast<const float4*>(&wt[od1 * 132 + 4 * k4]);
        #pragma unroll
        for (int j = 0; j < 4; ++j) {
            float4 h4 = *reinterpret_cast<const float4*>(&hs[(tg * 4 + j) * 128 + 4 * k4]);
            acc0[j] += h4.x * w0.x + h4.y * w0.y + h4.z * w0.z + h4.w * w0.w;
            acc1[j] += h4.x * w1.x + h4.y * w1.y + h4.z * w1.z + h4.w * w1.w;
        }
    }
    #pragma unroll
    for (int j = 0; j < 4; ++j) {
        int g = tg * 4 + j;
        atomicAdd(&out[g * ODIM + od0], acc0[j]);
        if (has1) atomicAdd(&out[g * ODIM + od1], acc1[j]);
    }
}

// ---------------------------------------------------------------------------
extern "C" void kernel_launch(void* const* d_in, const int* in_sizes, int n_in,
                              void* d_out, int out_size, void* d_ws, size_t ws_size,
                              hipStream_t stream) {
    const float* x    = (const float*)d_in[0];
    const int*   ei   = (const int*)d_in[1];
    const float* Wl   = (const float*)d_in[2];
    const float* bl   = (const float*)d_in[3];
    const float* Wr   = (const float*)d_in[4];
    const float* Wout = (const float*)d_in[5];
    const float* bout = (const float*)d_in[6];
    float* out = (float*)d_out;
    float* ws  = (float*)d_ws;

    float* xl  = ws + WS_XL;
    float* xr  = ws + WS_XR;
    float* agg = ws + WS_AGG;    // fast path: holds fused h
    float* cnt = ws + WS_CNT;    // fallback only

    if (ws_size >= WS_NEED_FAST) {
        uint*   gcount  = (uint*)(ws + WS_GCOUNT);
        ushort* pedge   = (ushort*)((char*)d_ws + PEDGE_BYTE_OFF);
        uint*   hist2   = (uint*)((char*)d_ws + HIST2_BYTE_OFF);
        uint*   seed2   = (uint*)((char*)d_ws + SEED2_BYTE_OFF);
        uint*   pedge0  = (uint*)((char*)d_ws + PEDGE0_BYTE_OFF);
        float*  partial = (float*)((char*)d_ws + PEDGE_BYTE_OFF); // after kS

        k1_lin<<<NTOT / 64, 256, 0, stream>>>(x, Wl, Wr, xl, xr);
        kT_pack<<<NEDGE / 4096, 1024, 0, stream>>>(ei, pedge0);
        kH2<<<NG * CH, 256, 0, stream>>>(pedge0, hist2);
        kScan2<<<NG, 256, 0, stream>>>(hist2, seed2, gcount);
        kB3<<<NG * CH, 256, 0, stream>>>(pedge0, hist2, seed2, pedge);
        kS_reg<<<NB, 256, 0, stream>>>(gcount, pedge, xl, xr, bl, agg);
        k4b_out<<<K4B, 256, 0, stream>>>(agg, Wout, partial);
        kR2_reduce<<<NG * PODS, 256, 0, stream>>>(partial, bout, out);
    } else {
        hipMemsetAsync(agg, 0, (size_t)(NTOT * HID + NTOT) * sizeof(float), stream);
        k1_lin<<<NTOT / 64, 256, 0, stream>>>(x, Wl, Wr, xl, xr);
        k2_edges<<<(long)NEDGE * 16 / 256, 256, 0, stream>>>(ei, xl, agg, cnt);
        k3_init_out<<<(NG * ODIM + 255) / 256, 256, 0, stream>>>(bout, out);
        k4_out<<<(NODES * HID) / 128, 256, 0, stream>>>(agg, cnt, xr, bl, Wout, out);
    }
}